// Round 14
// baseline (298.179 us; speedup 1.0000x reference)
//
#include <hip/hip_runtime.h>
#include <hip/hip_cooperative_groups.h>
#include <math.h>

namespace cg = cooperative_groups;

#define N 4096
#define D 512
#define MARGIN 0.05f
#define L2_REG 0.02f
#define N_POS 3
#define NCLASS 100
#define MAXC 128          // max members per class (expected ~41 +/- 7)
#define SLOTS 384         // 3*MAXC fixed pair slots per class

#define BM 128
#define BN 128
#define BK 64
#define NT (N / BM)           // 32 tiles per dim
#define NTILES (NT * (NT + 1) / 2)   // 528 triangular tiles
#define GRID 256              // == CU count: cooperative-safe at ANY occupancy >= 1 block/CU
#define KSTEPS (D / BK)       // 8

typedef unsigned short u16;
typedef __attribute__((ext_vector_type(8))) short bf16x8;
typedef __attribute__((ext_vector_type(8))) unsigned short u16x8;
typedef __attribute__((ext_vector_type(4))) float f32x4;

__device__ __forceinline__ u16 f2bf(float f) {
    unsigned u = __builtin_bit_cast(unsigned, f);
    unsigned r = u + 0x7fffu + ((u >> 16) & 1u);   // round-to-nearest-even
    return (u16)(r >> 16);
}

// Panel-major bf16 layout with baked-in XOR swizzle:
//   Xb2[((rb*8 + ks)*128 + r)*64 + (Q ^ (r&7))*8 + e] = X[rb*128+r][ks*64 + Q*8 + e]
// Each (row-block, k-step) panel is a contiguous 16 KB block; staging reads are
// fully coalesced; ds_read undoes the swizzle (conflict-free, 2-way max).

__global__ __launch_bounds__(256)
void fused_all(const float* __restrict__ X, const int* __restrict__ tgt,
               u16* __restrict__ Xb2, float* __restrict__ sqn, float* __restrict__ rown,
               float* __restrict__ l_n, int* __restrict__ cls_cnt,
               int2* __restrict__ pairs, float* __restrict__ out) {
    cg::grid_group grid = cg::this_grid();
    const int b = blockIdx.x, t = threadIdx.x;
    const int w = t >> 6, l = t & 63;

    __shared__ u16 As[BM * BK];   // 16 KB
    __shared__ u16 Bs[BN * BK];   // 16 KB
    __shared__ int idxs[MAXC];
    __shared__ int s_cnt, s_woff[4], s_wbase[4];

    // ================= Phase A: convert + norms + init + class pair lists =================
    #pragma unroll
    for (int rr = 0; rr < 4; ++rr) {
        int row = b * 16 + w * 4 + rr;      // GRID*16 == N exactly
        const float* xr = X + (size_t)row * D + l * 8;
        float4 v0 = *reinterpret_cast<const float4*>(xr);
        float4 v1 = *reinterpret_cast<const float4*>(xr + 4);
        u16x8 o;
        o[0] = f2bf(v0.x); o[1] = f2bf(v0.y); o[2] = f2bf(v0.z); o[3] = f2bf(v0.w);
        o[4] = f2bf(v1.x); o[5] = f2bf(v1.y); o[6] = f2bf(v1.z); o[7] = f2bf(v1.w);
        int rb = row >> 7, r = row & 127;
        int ks = l >> 3, Q = l & 7;
        size_t dst = (((size_t)(rb * 8 + ks) * 128 + r) * 64) + (size_t)((Q ^ (r & 7)) * 8);
        *reinterpret_cast<u16x8*>(Xb2 + dst) = o;
        float s = v0.x * v0.x + v0.y * v0.y + v0.z * v0.z + v0.w * v0.w
                + v1.x * v1.x + v1.y * v1.y + v1.z * v1.z + v1.w * v1.w;
        #pragma unroll
        for (int off = 32; off; off >>= 1) s += __shfl_xor(s, off);
        if (l == 0) { sqn[row] = s; rown[row] = sqrtf(s); }
    }
    if (t < 16) l_n[b * 16 + t] = 0.f;   // ws poisoned 0xAA; GRID*16 == N
    if (b == 0 && t == 0) out[0] = 0.f;

    if (b < NCLASS) {   // block-uniform branch; barriers inside are safe
        const int c = b;
        if (t == 0) s_cnt = 0;
        __syncthreads();
        for (int j0 = 0; j0 < N; j0 += 256) {
            int j = j0 + t;
            bool m = (tgt[j] == c);
            unsigned long long bal = __ballot(m);
            if ((t & 63) == 0) s_woff[t >> 6] = __popcll(bal);
            __syncthreads();
            if (t == 0) {
                int s = s_cnt;
                #pragma unroll
                for (int ww = 0; ww < 4; ++ww) { s_wbase[ww] = s; s += s_woff[ww]; }
                s_cnt = s;
            }
            __syncthreads();
            if (m) {
                int pos = s_wbase[t >> 6] + __popcll(bal & ((1ull << (t & 63)) - 1ull));
                if (pos < MAXC) idxs[pos] = j;
            }
            __syncthreads();
        }
        const int n  = s_cnt < MAXC ? s_cnt : MAXC;
        const int n1 = n - 1 > 0 ? n - 1 : 0;
        const int n2 = n - 2 > 0 ? n - 2 : 0;
        const int n3 = n - 3 > 0 ? n - 3 : 0;
        if (t == 0) cls_cnt[c] = n1 + n2 + n3;
        int2* reg = pairs + c * SLOTS;
        for (int s = t; s < SLOTS; s += 256) {
            int2 v = make_int2(-1, -1);
            if (s < n1)                v = make_int2(idxs[s], idxs[s + 1]);
            else if (s < n1 + n2)      { int p = s - n1;      v = make_int2(idxs[p], idxs[p + 2]); }
            else if (s < n1 + n2 + n3) { int p = s - n1 - n2; v = make_int2(idxs[p], idxs[p + 3]); }
            reg[s] = v;
        }
    }

    __threadfence();
    grid.sync();

    // ================= Phase B: triangular MFMA tiles, reg-prefetch pipeline =================
    const int wr = w >> 1, wc = w & 1;       // wave quadrant: 64x64 output
    const int lc = l & 15, lg = l >> 4;
    const int swz = lc & 7;

    for (int z = b; z < NTILES; z += GRID) {
        int bi = (int)((2 * NT + 1 - sqrtf((float)((2 * NT + 1) * (2 * NT + 1)) - 8.0f * (float)z)) * 0.5f);
        while (z <  bi * (2 * NT + 1 - bi) / 2) --bi;
        while (z >= (bi + 1) * (2 * NT - bi) / 2) ++bi;
        const int bj = bi + (z - bi * (2 * NT + 1 - bi) / 2);
        const int row0 = bi * BM, col0 = bj * BN;
        const bool offdiag = (bi != bj);

        f32x4 acc[4][4] = {};
        const u16* pa0 = Xb2 + (size_t)(bi * 8) * 128 * 64;
        const u16* pb0 = Xb2 + (size_t)(bj * 8) * 128 * 64;

        float4 sa[4], sb[4];
        #pragma unroll
        for (int q = 0; q < 4; ++q) {       // prologue: tile 0 -> regs
            size_t off = (size_t)((w * 256 + q * 64 + l) * 8);
            sa[q] = *reinterpret_cast<const float4*>(pa0 + off);
            sb[q] = *reinterpret_cast<const float4*>(pb0 + off);
        }

        for (int kt = 0; kt < KSTEPS; ++kt) {
            __syncthreads();                // all reads of previous tile done
            #pragma unroll
            for (int q = 0; q < 4; ++q) {   // regs -> LDS (linear; swizzle pre-baked)
                int pc = w * 256 + q * 64 + l;
                *reinterpret_cast<float4*>(&As[pc * 8]) = sa[q];
                *reinterpret_cast<float4*>(&Bs[pc * 8]) = sb[q];
            }
            __syncthreads();                // tile visible
            if (kt + 1 < KSTEPS) {          // prefetch next tile; flies under ds_read+MFMA
                const u16* pa = pa0 + (size_t)(kt + 1) * 128 * 64;
                const u16* pb = pb0 + (size_t)(kt + 1) * 128 * 64;
                #pragma unroll
                for (int q = 0; q < 4; ++q) {
                    size_t off = (size_t)((w * 256 + q * 64 + l) * 8);
                    sa[q] = *reinterpret_cast<const float4*>(pa + off);
                    sb[q] = *reinterpret_cast<const float4*>(pb + off);
                }
            }

            bf16x8 af[4][2], bfr[4][2];
            #pragma unroll
            for (int fm = 0; fm < 4; ++fm)
                #pragma unroll
                for (int ks = 0; ks < 2; ++ks) {
                    int row = wr * 64 + fm * 16 + lc;
                    int Q   = ks * 4 + lg;
                    af[fm][ks] = *reinterpret_cast<const bf16x8*>(&As[row * 64 + ((Q ^ swz) * 8)]);
                }
            #pragma unroll
            for (int fn = 0; fn < 4; ++fn)
                #pragma unroll
                for (int ks = 0; ks < 2; ++ks) {
                    int col = wc * 64 + fn * 16 + lc;
                    int Q   = ks * 4 + lg;
                    bfr[fn][ks] = *reinterpret_cast<const bf16x8*>(&Bs[col * 64 + ((Q ^ swz) * 8)]);
                }
            #pragma unroll
            for (int fm = 0; fm < 4; ++fm)
                #pragma unroll
                for (int fn = 0; fn < 4; ++fn) {
                    acc[fm][fn] = __builtin_amdgcn_mfma_f32_16x16x32_bf16(af[fm][0], bfr[fn][0], acc[fm][fn], 0, 0, 0);
                    acc[fm][fn] = __builtin_amdgcn_mfma_f32_16x16x32_bf16(af[fm][1], bfr[fn][1], acc[fm][fn], 0, 0, 0);
                }
        }

        // epilogue: C layout col = l&15, row = (l>>4)*4 + reg  [guide m89]
        int tgj[4]; float sqj[4];
        #pragma unroll
        for (int fn = 0; fn < 4; ++fn) {
            int gj = col0 + wc * 64 + fn * 16 + lc;
            tgj[fn] = tgt[gj]; sqj[fn] = sqn[gj];
        }
        float csum[4] = {};
        #pragma unroll
        for (int fm = 0; fm < 4; ++fm) {
            #pragma unroll
            for (int r = 0; r < 4; ++r) {
                int gi = row0 + wr * 64 + fm * 16 + lg * 4 + r;
                float sqi = sqn[gi]; int tgi = tgt[gi];
                float rs = 0.f;
                #pragma unroll
                for (int fn = 0; fn < 4; ++fn) {
                    float sq = sqi + sqj[fn] - 2.f * acc[fm][fn][r];
                    sq = fmaxf(sq, 0.f);
                    float dd = sq > 1e-12f ? sqrtf(sq) : 0.f;
                    float e = (tgi != tgj[fn]) ? __expf(MARGIN - dd) : 0.f;
                    rs += e;
                    csum[fn] += e;
                }
                rs += __shfl_xor(rs, 1); rs += __shfl_xor(rs, 2);
                rs += __shfl_xor(rs, 4); rs += __shfl_xor(rs, 8);
                if (lc == 0) atomicAdd(&l_n[gi], rs);
            }
        }
        if (offdiag) {
            #pragma unroll
            for (int fn = 0; fn < 4; ++fn) {
                float s = csum[fn];
                s += __shfl_xor(s, 16); s += __shfl_xor(s, 32);
                if (lg == 0) atomicAdd(&l_n[col0 + wc * 64 + fn * 16 + lc], s);
            }
        }
    }

    __threadfence();
    grid.sync();

    // ================= Phase C: pair loss + finalize =================
    {
        float local = 0.f;
        const int wid0 = b * 4 + w;
        for (int p = wid0; p < NCLASS * SLOTS; p += GRID * 4) {
            int2 pr = pairs[p];
            if (pr.x < 0) continue;     // sentinel (uniform across wave)
            const float* xi = X + (size_t)pr.x * D + l * 8;
            const float* xj = X + (size_t)pr.y * D + l * 8;
            float4 a0 = *reinterpret_cast<const float4*>(xi);
            float4 a1 = *reinterpret_cast<const float4*>(xi + 4);
            float4 b0 = *reinterpret_cast<const float4*>(xj);
            float4 b1 = *reinterpret_cast<const float4*>(xj + 4);
            float s = a0.x * b0.x + a0.y * b0.y + a0.z * b0.z + a0.w * b0.w
                    + a1.x * b1.x + a1.y * b1.y + a1.z * b1.z + a1.w * b1.w;
            #pragma unroll
            for (int off = 32; off; off >>= 1) s += __shfl_xor(s, off);
            if (l == 0) {
                float sq = sqn[pr.x] + sqn[pr.y] - 2.f * s;
                sq = fmaxf(sq, 0.f);
                float dd = sq > 1e-12f ? sqrtf(sq) : 0.f;
                float ln = logf(l_n[pr.x] + l_n[pr.y]);
                float pl = fmaxf(ln + dd, 0.f);
                local += pl * pl;
            }
        }
        __shared__ float wsum[4];
        __syncthreads();
        if (l == 0) wsum[w] = local;
        __syncthreads();
        if (t == 0) {
            int np = 0;
            for (int c = 0; c < NCLASS; ++c) np += cls_cnt[c];
            if (np > 0)
                atomicAdd(out, (wsum[0] + wsum[1] + wsum[2] + wsum[3]) / (float)np);
        }
        if (b == 0) {
            float s = 0.f;
            for (int i = t; i < N; i += 256) s += rown[i];
            #pragma unroll
            for (int off = 32; off; off >>= 1) s += __shfl_xor(s, off);
            __shared__ float nsum[4];
            if (l == 0) nsum[w] = s;
            __syncthreads();
            if (t == 0)
                atomicAdd(out, L2_REG * (nsum[0] + nsum[1] + nsum[2] + nsum[3]) / (float)N);
        }
    }
}

extern "C" void kernel_launch(void* const* d_in, const int* in_sizes, int n_in,
                              void* d_out, int out_size, void* d_ws, size_t ws_size,
                              hipStream_t stream) {
    const float* X   = (const float*)d_in[0];
    const int*   tgt = (const int*)d_in[1];

    u16*   Xb2 = (u16*)d_ws;                                  // N*D bf16 = 4 MB (panel-major)
    float* fw = (float*)((char*)d_ws + (size_t)N * D * 2);
    float* sqn     = fw;                // N
    float* rown    = fw + N;            // N
    float* l_n     = fw + 2 * N;        // N
    int*   cls_cnt = (int*)(fw + 3 * N);                      // NCLASS (pad to 128)
    int2*  pairs   = (int2*)(fw + 3 * N + 128);               // NCLASS*SLOTS int2
    float* outp    = (float*)d_out;

    void* args[] = {(void*)&X, (void*)&tgt, (void*)&Xb2, (void*)&sqn, (void*)&rown,
                    (void*)&l_n, (void*)&cls_cnt, (void*)&pairs, (void*)&outp};
    hipLaunchCooperativeKernel((const void*)fused_all, dim3(GRID), dim3(256), args, 0, stream);
}